// Round 3
// baseline (99.551 us; speedup 1.0000x reference)
//
#include <hip/hip_runtime.h>

#define BITS 108
#define RPB  256                     // rows per block (= threads per block)
#define WPT  432                     // u64 words per operand tile (256*108/64)

__global__ __launch_bounds__(256, 6) void rca108_kernel(
    const float* __restrict__ A, const float* __restrict__ B,
    float* __restrict__ S, float* __restrict__ C)
{
    __shared__ unsigned long long wA[WPT + 2];   // +2 pad: read-overrun guard
    __shared__ unsigned long long wB[WPT + 2];
    __shared__ ulonglong2 rowS[RPB];             // per-row sum bits {lo64, hi44}

    const int t = threadIdx.x;
    const int w = t >> 6;            // wave id 0..3
    const int l = t & 63;            // lane
    const size_t tile_base = (size_t)blockIdx.x * (RPB * BITS);

    const float* a = A + tile_base;
    const float* b = B + tile_base;

    // ---- Phase 1: ballot-pack. Word wi covers flat floats [wi*64, wi*64+64).
    // Wave w handles wi = i*4 + w; block streams contiguous 1 KB per i. ----
    #pragma unroll 6
    for (int i = 0; i < 108; ++i) {
        const int wi = i * 4 + w;
        const float av = a[wi * 64 + l];
        const float bv = b[wi * 64 + l];
        const unsigned long long ma = __ballot(av > 0.5f);
        const unsigned long long mb = __ballot(bv > 0.5f);
        if (l == 0) { wA[wi] = ma; wB[wi] = mb; }
    }
    if (t < 2) { wA[WPT + t] = 0; wB[WPT + t] = 0; }
    __syncthreads();

    // ---- Phase 2: thread t owns row t; extract 108 bits at flat bit 108*t,
    // do the exact 108-bit integer add, park sum bits in LDS. ----
    {
        const int bitpos = t * BITS;
        const int j0 = bitpos >> 6;
        const int o  = bitpos & 63;
        // (w1<<1)<<(63-o) == w1<<(64-o) for o>0, == 0 for o==0 (no UB shift-64)
        unsigned long long a0, a1, b0, b1;
        {
            const unsigned long long w0 = wA[j0], w1 = wA[j0 + 1], w2 = wA[j0 + 2];
            a0 = (w0 >> o) | ((w1 << 1) << (63 - o));
            a1 = ((w1 >> o) | ((w2 << 1) << (63 - o))) & ((1ull << 44) - 1ull);
        }
        {
            const unsigned long long w0 = wB[j0], w1 = wB[j0 + 1], w2 = wB[j0 + 2];
            b0 = (w0 >> o) | ((w1 << 1) << (63 - o));
            b1 = ((w1 >> o) | ((w2 << 1) << (63 - o))) & ((1ull << 44) - 1ull);
        }
        const unsigned long long s0 = a0 + b0;
        const unsigned long long cy = (s0 < a0) ? 1ull : 0ull;
        const unsigned long long s1 = a1 + b1 + cy;
        rowS[t] = make_ulonglong2(s0, s1);
        C[blockIdx.x * RPB + t] = (float)((s1 >> 44) & 1ull);
    }
    __syncthreads();

    // ---- Phase 3: coalesced float4 stores; each float4 lies inside one row
    // (108 % 4 == 0), gather its 4 sum bits from rowS (mostly broadcast). ----
    float4* s4 = reinterpret_cast<float4*>(S + tile_base);
    #pragma unroll
    for (int i = 0; i < 27; ++i) {
        const int idx = i * 256 + t;              // float4 index within tile
        const int r   = idx / 27;                 // row = (4*idx)/108
        const int off = (idx - r * 27) * 4;       // bit offset, multiple of 4
        const ulonglong2 sv = rowS[r];
        const unsigned long long src =
            (off < 64) ? (sv.x >> off) : (sv.y >> (off - 64));
        float4 v;
        v.x = (float)( src        & 1ull);
        v.y = (float)((src >> 1)  & 1ull);
        v.z = (float)((src >> 2)  & 1ull);
        v.w = (float)((src >> 3)  & 1ull);
        s4[idx] = v;
    }
}

extern "C" void kernel_launch(void* const* d_in, const int* in_sizes, int n_in,
                              void* d_out, int out_size, void* d_ws, size_t ws_size,
                              hipStream_t stream) {
    const float* A = (const float*)d_in[0];
    const float* B = (const float*)d_in[1];
    float* S = (float*)d_out;                    // [nrows, 108] flat
    const int nrows = in_sizes[0] / BITS;        // 262144
    float* C = S + (size_t)nrows * BITS;         // [nrows, 1] after S

    const int grid = nrows / RPB;                // 1024 (exact)
    rca108_kernel<<<grid, RPB, 0, stream>>>(A, B, S, C);
}

// Round 4
// 71.441 us; speedup vs baseline: 1.3935x; 1.3935x over previous
//
#include <hip/hip_runtime.h>

#define BITS 108
#define RPB  256                      // rows per block (= threads per block)
#define WPR  27                       // u32 words per row (1 byte per float)
#define TILE_WORDS (RPB * WPR)        // 6912 u32 = 27,648 B

// LDS byte layout: byte per float, bit0 = A bit, bit1 = B bit.
__global__ __launch_bounds__(256, 5) void rca108_kernel(
    const float* __restrict__ A, const float* __restrict__ B,
    float* __restrict__ S, float* __restrict__ C)
{
    __shared__ unsigned int ldsAB[TILE_WORDS];   // 27,648 B
    __shared__ ulonglong2 rowS[RPB];             // 4,096 B: per-row sum bits

    const int t = threadIdx.x;
    const size_t tile_base = (size_t)blockIdx.x * (RPB * BITS);  // floats

    const float4* a4 = reinterpret_cast<const float4*>(A + tile_base);
    const float4* b4 = reinterpret_cast<const float4*>(B + tile_base);

    // ---- Phase 1: coalesced dwordx4 loads; pack A|B into one byte/float ----
    #pragma unroll
    for (int i = 0; i < WPR; ++i) {
        const int idx = i * RPB + t;             // float4 index == LDS word idx
        const float4 av = a4[idx];
        const float4 bv = b4[idx];
        const unsigned int w =
              (unsigned)(av.x > 0.5f)        | ((unsigned)(bv.x > 0.5f) << 1)
            | ((unsigned)(av.y > 0.5f) << 8) | ((unsigned)(bv.y > 0.5f) << 9)
            | ((unsigned)(av.z > 0.5f) << 16)| ((unsigned)(bv.z > 0.5f) << 17)
            | ((unsigned)(av.w > 0.5f) << 24)| ((unsigned)(bv.w > 0.5f) << 25);
        ldsAB[idx] = w;
    }
    __syncthreads();

    // ---- Phase 2: thread t owns row t; gather 27 words -> 108-bit A and B,
    // exact integer add, park sum bits in rowS. ----
    {
        unsigned long long a0 = 0, a1 = 0, b0 = 0, b1 = 0;
        #pragma unroll
        for (int j = 0; j < WPR; ++j) {
            const unsigned int w = ldsAB[t * WPR + j];
            // collapse the 4 bytes' bit0s (A) and bit1s (B) into nibbles
            const unsigned int wa = w & 0x01010101u;
            const unsigned int wb = (w >> 1) & 0x01010101u;
            const unsigned long long na = (unsigned long long)(((wa * 0x01020408u) >> 24) & 0xFu);
            const unsigned long long nb = (unsigned long long)(((wb * 0x01020408u) >> 24) & 0xFu);
            if (j < 16) { a0 |= na << (4 * j);        b0 |= nb << (4 * j); }
            else        { a1 |= na << (4 * (j - 16)); b1 |= nb << (4 * (j - 16)); }
        }
        const unsigned long long s0 = a0 + b0;
        const unsigned long long cy = (s0 < a0) ? 1ull : 0ull;
        const unsigned long long s1 = a1 + b1 + cy;
        rowS[t] = make_ulonglong2(s0, s1);
        C[blockIdx.x * RPB + t] = (float)((s1 >> 44) & 1ull);
    }
    __syncthreads();

    // ---- Phase 3: coalesced float4 stores; each float4 lies inside one row
    // (108 % 4 == 0); gather its 4 bits from rowS (mostly broadcast reads). ----
    float4* s4 = reinterpret_cast<float4*>(S + tile_base);
    #pragma unroll
    for (int i = 0; i < WPR; ++i) {
        const int idx = i * RPB + t;              // float4 index within tile
        const int r   = idx / WPR;                // owning row
        const int off = (idx - r * WPR) * 4;      // bit offset, multiple of 4
        const ulonglong2 sv = rowS[r];
        const unsigned long long src =
            (off < 64) ? (sv.x >> off) : (sv.y >> (off - 64));
        float4 v;
        v.x = (float)( src        & 1ull);
        v.y = (float)((src >> 1)  & 1ull);
        v.z = (float)((src >> 2)  & 1ull);
        v.w = (float)((src >> 3)  & 1ull);
        s4[idx] = v;
    }
}

extern "C" void kernel_launch(void* const* d_in, const int* in_sizes, int n_in,
                              void* d_out, int out_size, void* d_ws, size_t ws_size,
                              hipStream_t stream) {
    const float* A = (const float*)d_in[0];
    const float* B = (const float*)d_in[1];
    float* S = (float*)d_out;                    // [nrows, 108] flat
    const int nrows = in_sizes[0] / BITS;        // 262144
    float* C = S + (size_t)nrows * BITS;         // [nrows, 1] after S

    const int grid = nrows / RPB;                // 1024 (exact)
    rca108_kernel<<<grid, RPB, 0, stream>>>(A, B, S, C);
}

// Round 6
// 53.106 us; speedup vs baseline: 1.8746x; 1.3452x over previous
//
#include <hip/hip_runtime.h>

#define BITS 108
#define RPB  64                       // rows per block = threads per block (1 wave)
#define WPR  27                       // u32 words per row (1 byte per float)
#define TILE_WORDS (RPB * WPR)        // 1728 u32 = 6912 B

typedef float f32x4 __attribute__((ext_vector_type(4)));

// LDS byte layout: byte per float, bit0 = A bit, bit1 = B bit.
__global__ __launch_bounds__(64) void rca108_kernel(
    const float* __restrict__ A, const float* __restrict__ B,
    float* __restrict__ S, float* __restrict__ C)
{
    __shared__ unsigned int ldsAB[TILE_WORDS];   // 6,912 B
    __shared__ ulonglong2 rowS[RPB];             // 1,024 B

    const int t = threadIdx.x;                   // 0..63 (one wave)
    const size_t tile_base = (size_t)blockIdx.x * (RPB * BITS);  // floats

    const f32x4* a4 = reinterpret_cast<const f32x4*>(A + tile_base);
    const f32x4* b4 = reinterpret_cast<const f32x4*>(B + tile_base);

    // ---- Phase 1: coalesced dwordx4 loads; pack A|B into one byte/float ----
    #pragma unroll
    for (int i = 0; i < WPR; ++i) {
        const int idx = i * RPB + t;             // float4 index == LDS word idx
        const f32x4 av = a4[idx];
        const f32x4 bv = b4[idx];
        const unsigned int w =
              (unsigned)(av.x > 0.5f)        | ((unsigned)(bv.x > 0.5f) << 1)
            | ((unsigned)(av.y > 0.5f) << 8) | ((unsigned)(bv.y > 0.5f) << 9)
            | ((unsigned)(av.z > 0.5f) << 16)| ((unsigned)(bv.z > 0.5f) << 17)
            | ((unsigned)(av.w > 0.5f) << 24)| ((unsigned)(bv.w > 0.5f) << 25);
        ldsAB[idx] = w;
    }
    __syncthreads();                             // single-wave: near-free

    // ---- Phase 2: thread t owns row t; gather 27 words -> 108-bit A and B,
    // exact integer add, park sum bits in rowS. ----
    {
        unsigned long long a0 = 0, a1 = 0, b0 = 0, b1 = 0;
        #pragma unroll
        for (int j = 0; j < WPR; ++j) {
            const unsigned int w = ldsAB[t * WPR + j];   // stride 27: conflict-free
            const unsigned int wa = w & 0x01010101u;
            const unsigned int wb = (w >> 1) & 0x01010101u;
            const unsigned long long na = (unsigned long long)(((wa * 0x01020408u) >> 24) & 0xFu);
            const unsigned long long nb = (unsigned long long)(((wb * 0x01020408u) >> 24) & 0xFu);
            if (j < 16) { a0 |= na << (4 * j);        b0 |= nb << (4 * j); }
            else        { a1 |= na << (4 * (j - 16)); b1 |= nb << (4 * (j - 16)); }
        }
        const unsigned long long s0 = a0 + b0;
        const unsigned long long cy = (s0 < a0) ? 1ull : 0ull;
        const unsigned long long s1 = a1 + b1 + cy;
        rowS[t] = make_ulonglong2(s0, s1);
        __builtin_nontemporal_store((float)((s1 >> 44) & 1ull),
                                    &C[blockIdx.x * RPB + t]);
    }
    __syncthreads();

    // ---- Phase 3: coalesced float4 stores; each float4 lies inside one row
    // (108 % 4 == 0); gather its 4 bits from rowS (broadcast-friendly). ----
    f32x4* s4 = reinterpret_cast<f32x4*>(S + tile_base);
    #pragma unroll
    for (int i = 0; i < WPR; ++i) {
        const int idx = i * RPB + t;              // float4 index within tile
        const int r   = idx / WPR;                // owning row (0..63)
        const int off = (idx - r * WPR) * 4;      // bit offset, multiple of 4
        const ulonglong2 sv = rowS[r];
        const unsigned long long src =
            (off < 64) ? (sv.x >> off) : (sv.y >> (off - 64));
        f32x4 v;
        v.x = (float)( src        & 1ull);
        v.y = (float)((src >> 1)  & 1ull);
        v.z = (float)((src >> 2)  & 1ull);
        v.w = (float)((src >> 3)  & 1ull);
        __builtin_nontemporal_store(v, &s4[idx]);
    }
}

extern "C" void kernel_launch(void* const* d_in, const int* in_sizes, int n_in,
                              void* d_out, int out_size, void* d_ws, size_t ws_size,
                              hipStream_t stream) {
    const float* A = (const float*)d_in[0];
    const float* B = (const float*)d_in[1];
    float* S = (float*)d_out;                    // [nrows, 108] flat
    const int nrows = in_sizes[0] / BITS;        // 262144
    float* C = S + (size_t)nrows * BITS;         // [nrows, 1] after S

    const int grid = nrows / RPB;                // 4096 (exact)
    rca108_kernel<<<grid, RPB, 0, stream>>>(A, B, S, C);
}

// Round 7
// 51.888 us; speedup vs baseline: 1.9186x; 1.0235x over previous
//
#include <hip/hip_runtime.h>

#define BITS 108
#define F4PR 27                 // float4s per row
#define ACT  54                 // active lanes per wave = 2 rows

typedef float f32x4 __attribute__((ext_vector_type(4)));

// One wave = 2 rows. Lane l<27: row 2w pos l; 27<=l<54: row 2w+1 pos l-27.
// Per-lane 4-bit nibble add with carry via segmented Kogge-Stone scan of
// (G,P) pairs packed into one register (bit0=G, bit1=P, bit2=segment flag).
__global__ __launch_bounds__(256) void rca108_kernel(
    const f32x4* __restrict__ A4, const f32x4* __restrict__ B4,
    f32x4* __restrict__ S4, float* __restrict__ C)
{
    const int gtid = blockIdx.x * blockDim.x + threadIdx.x;
    const int wid  = gtid >> 6;                 // global wave id
    const int l    = threadIdx.x & 63;
    const int pos  = (l < F4PR) ? l : l - F4PR; // >=27 for idle lanes: harmless
    const int li   = (l < ACT) ? l : (ACT - 1); // clamp idle lanes' address
    const size_t g = (size_t)wid * ACT + li;    // float4 index

    const f32x4 av = A4[g];
    const f32x4 bv = B4[g];
    const unsigned an = (unsigned)(av.x > 0.5f)
                      | ((unsigned)(av.y > 0.5f) << 1)
                      | ((unsigned)(av.z > 0.5f) << 2)
                      | ((unsigned)(av.w > 0.5f) << 3);
    const unsigned bn = (unsigned)(bv.x > 0.5f)
                      | ((unsigned)(bv.y > 0.5f) << 1)
                      | ((unsigned)(bv.z > 0.5f) << 2)
                      | ((unsigned)(bv.w > 0.5f) << 3);
    const unsigned sum = an + bn;                       // 0..30
    const unsigned Gn  = sum >> 4;                      // generate
    const unsigned Pn  = ((sum & 0xFu) == 0xFu) ? 1u : 0u;  // propagate

    // Exclusive segmented scan: shift (G,P) up by 1; segment starts (pos==0)
    // get identity (G=0,P=1) with flag set.
    const unsigned v    = Gn | (Pn << 1);
    const unsigned prev = __shfl_up(v, 1);              // all lanes execute
    unsigned x = (pos == 0) ? (0u | (1u << 1) | (1u << 2)) : prev;

    // Kogge-Stone, max segment length 27 -> d up to 16.
    #pragma unroll
    for (int d = 1; d <= 16; d <<= 1) {
        const unsigned y = __shfl_up(x, d);             // all lanes execute
        const bool take = (l >= d) && ((x & 4u) == 0u);
        const unsigned Ghi = x & 1u, Phi = (x >> 1) & 1u;
        const unsigned Glo = y & 1u, Plo = (y >> 1) & 1u;
        const unsigned comb = (Ghi | (Phi & Glo))
                            | ((Phi & Plo) << 1)
                            | ((x | y) & 4u);
        x = take ? comb : x;
    }
    const unsigned cin = x & 1u;                        // carry into this nibble
    const unsigned s   = sum + cin;                     // 5 bits

    f32x4 out;
    out.x = (float)( s       & 1u);
    out.y = (float)((s >> 1) & 1u);
    out.z = (float)((s >> 2) & 1u);
    out.w = (float)((s >> 3) & 1u);
    if (l < ACT) {
        __builtin_nontemporal_store(out, &S4[g]);
        if (pos == F4PR - 1) {                          // top nibble of a row
            const int row = wid * 2 + (l >= F4PR);
            __builtin_nontemporal_store((float)(s >> 4), &C[row]);
        }
    }
}

extern "C" void kernel_launch(void* const* d_in, const int* in_sizes, int n_in,
                              void* d_out, int out_size, void* d_ws, size_t ws_size,
                              hipStream_t stream) {
    const f32x4* A4 = (const f32x4*)d_in[0];
    const f32x4* B4 = (const f32x4*)d_in[1];
    float* S = (float*)d_out;                     // [nrows, 108] flat
    const int nrows = in_sizes[0] / BITS;         // 262144
    float* C = S + (size_t)nrows * BITS;          // [nrows, 1] after S

    const int nwaves = nrows / 2;                 // 131072
    const int threads = nwaves * 64;              // 8,388,608
    const int block = 256;
    const int grid = threads / block;             // 32768 (exact)
    rca108_kernel<<<grid, block, 0, stream>>>(A4, B4, (f32x4*)S, C);
}